// Round 7
// baseline (924.078 us; speedup 1.0000x reference)
//
#include <hip/hip_runtime.h>
#include <hip/hip_fp16.h>

// Output layout (flat): forces[n_atoms*3] | virial[n_images*9] | stress[n_images*9]
//
// v13: the ~300us invariant across v8-v12 tracks the image_idx[ij.x] RANDOM
// GATHER (present in every slow kernel, absent from every fast one; CAS vs
// native LDS atomics made no difference -- v8==v11, v9==v10). image_idx is
// SORTED in this problem, so replace the gather with a 129-entry CSR boundary
// array (built once) + 7-step binary search in LDS inside k_scatter.
// Also: BASHIFT 11 (nb=98) to shrink the direct-scatter open-line set, and
// pipeline consolidated to 6 kernels (single-block scan; vreduce+stress fused)
// so rocprof top-5 shows the full breakdown.

typedef unsigned int uint;
typedef unsigned short ushort;

#define SLICES  1024        // count/scatter blocks (512 threads each)
#define BASHIFT 11          // 2048 atoms per bucket
#define NBCAP   128         // max buckets (n_atoms <= 256k)
#define NVMAX   1152        // n_images*9 cap (n_images <= 128)
#define GT      512         // gather block size
#define GSPLIT  8           // gather blocks per bucket
#define BATOMS  (1 << BASHIFT)

__device__ __forceinline__ uint pack_h2(float a, float b) {
    const __half2 h = __floats2half2_rn(a, b);
    return *(const uint*)&h;
}

// ---------------- K1: per-(slice,bucket) histogram ----------------
__global__ __launch_bounds__(512) void k_count(
    const int2* __restrict__ edge_idx, uint* __restrict__ counts,
    int n_edges, int es, int nb)
{
    __shared__ uint hist[NBCAP];
    for (int t = threadIdx.x; t < nb; t += blockDim.x) hist[t] = 0;
    __syncthreads();
    const int s  = blockIdx.x;
    const int e0 = s * es;
    const int e1 = min(n_edges, e0 + es);
    for (int e = e0 + threadIdx.x; e < e1; e += blockDim.x) {
        const int2 ij = edge_idx[e];
        atomicAdd(&hist[((uint)ij.x) >> BASHIFT], 1u);
        atomicAdd(&hist[((uint)ij.y) >> BASHIFT], 1u);
    }
    __syncthreads();
    for (int b = threadIdx.x; b < nb; b += blockDim.x)
        counts[(size_t)b * SLICES + s] = hist[b];   // bucket-major
}

// ---------------- K1b: image CSR boundaries (image_idx is sorted) -------
// bnd pre-memset to 0x7f7f7f7f; transition atoms record their index.
__global__ __launch_bounds__(512) void k_bounds(
    const int* __restrict__ image_idx, uint* __restrict__ bnd, int n_atoms)
{
    const int t = blockIdx.x * blockDim.x + threadIdx.x;
    if (t >= n_atoms) return;
    const int img = image_idx[t];
    if (t == 0 || image_idx[t - 1] != img) atomicMin(&bnd[img], (uint)t);
}

// ---------------- K2: single-block exclusive scan + bnd fixup ----------
__global__ __launch_bounds__(1024) void k_scan(
    uint* __restrict__ counts, uint* __restrict__ bnd, int N, int n_atoms)
{
    __shared__ uint wtot[16], wpre[16];
    const int tid = threadIdx.x, lane = tid & 63, wid = tid >> 6;
    const int chunk = (N + 1023) >> 10;
    const int a0 = tid * chunk, a1 = min(N, a0 + chunk);
    uint sum = 0;
    for (int a = a0; a < a1; ++a) sum += counts[a];
    uint v = sum;
    #pragma unroll
    for (int off = 1; off < 64; off <<= 1) {
        const uint n = __shfl_up(v, off, 64);
        if (lane >= off) v += n;
    }
    if (lane == 63) wtot[wid] = v;
    __syncthreads();
    if (wid == 0) {
        uint t2 = (lane < 16) ? wtot[lane] : 0u;
        #pragma unroll
        for (int off = 1; off < 16; off <<= 1) {
            const uint n = __shfl_up(t2, off, 64);
            if (lane >= off) t2 += n;
        }
        if (lane < 16) wpre[lane] = t2 - wtot[lane];
    }
    __syncthreads();
    uint run = v - sum + wpre[wid];                 // exclusive prefix
    for (int a = a0; a < a1; ++a) { const uint c = counts[a]; counts[a] = run; run += c; }

    if (tid == 0) {                                 // CSR fixup (suffix min)
        bnd[128] = (uint)n_atoms;
        for (int m = 127; m >= 0; --m) bnd[m] = min(bnd[m], bnd[m + 1]);
    }
}

// ---------------- K3: direct counting-sort scatter + virial ------------
// entry (uint2): x=h2(dEx,dEy)  y=h(dEz) | local<<16   (local < 2048)
// j-entries: sign-flipped dE (fp16 sign-bit XOR).
// Zero barriers in the main loop; LDS uint cursors hand out absolute slots.
// Image of atom i via 7-step binary search over LDS CSR bounds (no global
// gather -- the gather was the ~300us invariant in v8-v12).
__global__ __launch_bounds__(512) void k_scatter(
    const float* __restrict__ edge_diff, const float* __restrict__ dE_ddiff,
    const int2* __restrict__ edge_idx,
    const uint* __restrict__ offsets, const uint* __restrict__ bnd,
    uint2* __restrict__ entries, float* __restrict__ vpart,
    int n_edges, int es, int nb, int nv)
{
    __shared__ uint  gcur[NBCAP];
    __shared__ float v_lds[NVMAX];
    __shared__ uint  bnd_s[129];
    const int s   = blockIdx.x;
    const int tid = threadIdx.x;
    for (int t = tid; t < nb; t += blockDim.x)
        gcur[t] = offsets[(size_t)t * SLICES + s];
    for (int t = tid; t < nv; t += blockDim.x) v_lds[t] = 0.f;
    for (int t = tid; t < 129; t += blockDim.x) bnd_s[t] = bnd[t];
    __syncthreads();

    const int e0 = s * es;
    const int e1 = min(n_edges, e0 + es);
    const uint mask = (1u << BASHIFT) - 1u;

    for (int e = e0 + tid; e < e1; e += blockDim.x) {
        const int2 ij = edge_idx[e];
        const float dx = dE_ddiff[3*e + 0];
        const float dy = dE_ddiff[3*e + 1];
        const float dz = dE_ddiff[3*e + 2];
        const uint ai = (uint)ij.x, aj = (uint)ij.y;
        const uint dzh = (uint)__half_as_ushort(__float2half_rn(dz));
        uint2 ei, ej;
        ei.x = pack_h2(dx, dy);
        ei.y = dzh | ((ai & mask) << 16);
        ej.x = ei.x ^ 0x80008000u;                       // -dx, -dy
        ej.y = (dzh ^ 0x8000u) | ((aj & mask) << 16);    // -dz

        const uint di = atomicAdd(&gcur[ai >> BASHIFT], 1u);
        entries[di] = ei;
        const uint dj = atomicAdd(&gcur[aj >> BASHIFT], 1u);
        entries[dj] = ej;

        // image of atom i: largest m with bnd[m] <= ai (CSR binary search)
        uint lo = 0;
        #pragma unroll
        for (int st = 64; st > 0; st >>= 1) {
            const uint c = lo + st;
            if (bnd_s[c] <= ai) lo = c;
        }

        const float ex = edge_diff[3*e + 0];
        const float ey = edge_diff[3*e + 1];
        const float ez = edge_diff[3*e + 2];
        float* v = &v_lds[lo * 9];
        unsafeAtomicAdd(&v[0], ex*dx); unsafeAtomicAdd(&v[1], ex*dy); unsafeAtomicAdd(&v[2], ex*dz);
        unsafeAtomicAdd(&v[3], ey*dx); unsafeAtomicAdd(&v[4], ey*dy); unsafeAtomicAdd(&v[5], ey*dz);
        unsafeAtomicAdd(&v[6], ez*dx); unsafeAtomicAdd(&v[7], ez*dy); unsafeAtomicAdd(&v[8], ez*dz);
    }
    __syncthreads();
    for (int t = tid; t < nv; t += blockDim.x)
        vpart[(size_t)s * nv + t] = v_lds[t];            // coalesced partials
}

// ---------------- K4: gather -> forces (8 splits per bucket) ----------
__device__ __forceinline__ void proc_entry(uint2 e, float* tile) {
    const float2 dxy = __half22float2(*(const __half2*)&e.x);
    const float  dz  = __half2float(__ushort_as_half((ushort)(e.y & 0xffffu)));
    const uint local = (e.y >> 16) & (BATOMS - 1u);
    unsafeAtomicAdd(&tile[local*3 + 0], dxy.x);
    unsafeAtomicAdd(&tile[local*3 + 1], dxy.y);
    unsafeAtomicAdd(&tile[local*3 + 2], dz);
}

__global__ __launch_bounds__(GT) void k_gather(
    const uint2* __restrict__ entries, const uint* __restrict__ offsets,
    float* __restrict__ forces /* zeroed */,
    int n_atoms, int nb, uint total)
{
    __shared__ float tile[3 * BATOMS];   // 24 KB block-level

    const int q     = blockIdx.x / GSPLIT;
    const int split = blockIdx.x - q * GSPLIT;
    const int tid   = threadIdx.x;
    const int batom = q << BASHIFT;

    for (int t = tid; t < 3 * BATOMS; t += GT) tile[t] = 0.f;
    __syncthreads();

    const uint beg = offsets[(size_t)q * SLICES];
    const uint end = (q + 1 < nb) ? offsets[(size_t)(q + 1) * SLICES] : total;
    const uint len = end - beg;
    const uint s0  = beg + (uint)(((unsigned long long)len *  split     ) / GSPLIT);
    const uint s1  = beg + (uint)(((unsigned long long)len * (split + 1)) / GSPLIT);

    // 4-wide unrolled main loop: 4 outstanding 8B loads per thread
    const uint step = GT;
    uint k = s0 + tid;
    while (k + 3u * step < s1) {
        const uint2 e0 = entries[k];
        const uint2 e1 = entries[k +      step];
        const uint2 e2 = entries[k + 2u * step];
        const uint2 e3 = entries[k + 3u * step];
        proc_entry(e0, tile);
        proc_entry(e1, tile);
        proc_entry(e2, tile);
        proc_entry(e3, tile);
        k += 4u * step;
    }
    for (; k < s1; k += step)
        proc_entry(entries[k], tile);

    __syncthreads();

    const int nvalid = min(n_atoms - batom, BATOMS);
    const int lim3 = nvalid * 3;
    for (int t = tid; t < lim3; t += GT) {
        const float val = tile[t];
        if (val != 0.f) unsafeAtomicAdd(&forces[(size_t)batom * 3 + t], val);
    }
}

// ---------------- K5: virial reduce + stress (fused) ----------------
__global__ __launch_bounds__(256) void k_vfinal(
    const float* __restrict__ vpart, const float* __restrict__ cell,
    float* __restrict__ virial, float* __restrict__ stress, int nv)
{
    const int t = blockIdx.x * 256 + threadIdx.x;
    if (t >= nv) return;
    float acc = 0.f;
    #pragma unroll 8
    for (int s = 0; s < SLICES; ++s) acc += vpart[(size_t)s * nv + t];
    virial[t] = acc;
    const float* c = &cell[(t / 9) * 9];
    const float crx = c[4]*c[8] - c[5]*c[7];
    const float cry = c[5]*c[6] - c[3]*c[8];
    const float crz = c[3]*c[7] - c[4]*c[6];
    const float vol = c[0]*crx + c[1]*cry + c[2]*crz;
    stress[t] = acc * (-1.0f / vol);
}

// ---------------- fallback (round-1) path ----------------
__global__ __launch_bounds__(256) void edge_kernel_fb(
    const float* __restrict__ edge_diff, const float* __restrict__ dE_ddiff,
    const int2* __restrict__ edge_idx, const int* __restrict__ image_idx,
    float* __restrict__ forces, float* __restrict__ virial,
    int n_edges, int n_images)
{
    extern __shared__ float lds_v[];
    const int nv = n_images * 9;
    for (int t = threadIdx.x; t < nv; t += blockDim.x) lds_v[t] = 0.f;
    __syncthreads();
    const int stride = gridDim.x * blockDim.x;
    for (int e = blockIdx.x * blockDim.x + threadIdx.x; e < n_edges; e += stride) {
        const int2 ij = edge_idx[e];
        const int i = ij.x, j = ij.y;
        const float dx = dE_ddiff[3*e+0], dy = dE_ddiff[3*e+1], dz = dE_ddiff[3*e+2];
        unsafeAtomicAdd(&forces[3*i+0],  dx);
        unsafeAtomicAdd(&forces[3*i+1],  dy);
        unsafeAtomicAdd(&forces[3*i+2],  dz);
        unsafeAtomicAdd(&forces[3*j+0], -dx);
        unsafeAtomicAdd(&forces[3*j+1], -dy);
        unsafeAtomicAdd(&forces[3*j+2], -dz);
        const float ex = edge_diff[3*e+0], ey = edge_diff[3*e+1], ez = edge_diff[3*e+2];
        float* v = &lds_v[image_idx[i] * 9];
        unsafeAtomicAdd(&v[0], ex*dx); unsafeAtomicAdd(&v[1], ex*dy); unsafeAtomicAdd(&v[2], ex*dz);
        unsafeAtomicAdd(&v[3], ey*dx); unsafeAtomicAdd(&v[4], ey*dy); unsafeAtomicAdd(&v[5], ey*dz);
        unsafeAtomicAdd(&v[6], ez*dx); unsafeAtomicAdd(&v[7], ez*dy); unsafeAtomicAdd(&v[8], ez*dz);
    }
    __syncthreads();
    for (int t = threadIdx.x; t < nv; t += blockDim.x) {
        const float val = lds_v[t];
        if (val != 0.f) unsafeAtomicAdd(&virial[t], val);
    }
}

__global__ void k_stress_fb(const float* __restrict__ cell,
                            const float* __restrict__ virial,
                            float* __restrict__ stress, int n_images)
{
    const int t = blockIdx.x * blockDim.x + threadIdx.x;
    if (t >= n_images * 9) return;
    const float* c = &cell[(t / 9) * 9];
    const float crx = c[4]*c[8] - c[5]*c[7];
    const float cry = c[5]*c[6] - c[3]*c[8];
    const float crz = c[3]*c[7] - c[4]*c[6];
    const float vol = c[0]*crx + c[1]*cry + c[2]*crz;
    stress[t] = virial[t] * (-1.0f / vol);
}

extern "C" void kernel_launch(void* const* d_in, const int* in_sizes, int n_in,
                              void* d_out, int out_size, void* d_ws, size_t ws_size,
                              hipStream_t stream)
{
    const float* edge_diff = (const float*)d_in[0];
    const float* dE_ddiff  = (const float*)d_in[1];
    const float* cell      = (const float*)d_in[2];
    const int2*  edge_idx  = (const int2*)d_in[3];
    const int*   image_idx = (const int*)d_in[4];

    const int n_edges  = in_sizes[0] / 3;
    const int n_images = in_sizes[2] / 9;
    const int n_atoms  = in_sizes[4];
    const int nv       = n_images * 9;

    float* out    = (float*)d_out;
    float* forces = out;
    float* virial = out + (size_t)n_atoms * 3;
    float* stress = virial + nv;

    const int nb = (n_atoms + BATOMS - 1) >> BASHIFT;
    const int es = (n_edges + SLICES - 1) / SLICES;
    const uint total = (uint)(2 * (size_t)n_edges);

    const size_t entries_bytes = (size_t)total * sizeof(uint2);
    const size_t counts_bytes  = (size_t)NBCAP * SLICES * sizeof(uint);
    const size_t bnd_bytes     = 256 * sizeof(uint);
    const size_t vpart_bytes   = (size_t)SLICES * NVMAX * sizeof(float);
    const size_t need = entries_bytes + counts_bytes + bnd_bytes + vpart_bytes;

    if (ws_size >= need && nb <= NBCAP && nv <= NVMAX && n_images <= 128) {
        uint2* entries = (uint2*)d_ws;
        uint*  offsets = (uint*)((char*)d_ws + entries_bytes);
        uint*  bnd     = offsets + (size_t)NBCAP * SLICES;
        float* vpart   = (float*)(bnd + 256);

        hipMemsetAsync(bnd, 0x7f, 129 * sizeof(uint), stream);
        hipMemsetAsync(forces, 0, (size_t)n_atoms * 3 * sizeof(float), stream);

        k_count<<<SLICES, 512, 0, stream>>>(edge_idx, offsets, n_edges, es, nb);
        k_bounds<<<(n_atoms + 511) / 512, 512, 0, stream>>>(image_idx, bnd, n_atoms);
        k_scan<<<1, 1024, 0, stream>>>(offsets, bnd, nb * SLICES, n_atoms);
        k_scatter<<<SLICES, 512, 0, stream>>>(edge_diff, dE_ddiff, edge_idx,
                                              offsets, bnd, entries, vpart,
                                              n_edges, es, nb, nv);
        k_gather<<<nb * GSPLIT, GT, 0, stream>>>(entries, offsets, forces,
                                                 n_atoms, nb, total);
        k_vfinal<<<(nv + 255) / 256, 256, 0, stream>>>(vpart, cell, virial, stress, nv);
    } else {
        hipMemsetAsync(out, 0, ((size_t)n_atoms * 3 + nv) * sizeof(float), stream);
        edge_kernel_fb<<<2048, 256, nv * sizeof(float), stream>>>(
            edge_diff, dE_ddiff, edge_idx, image_idx, forces, virial, n_edges, n_images);
        k_stress_fb<<<(nv + 255) / 256, 256, 0, stream>>>(cell, virial, stress, n_images);
    }
}